// Round 6
// baseline (7504.352 us; speedup 1.0000x reference)
//
#include <hip/hip_runtime.h>
#include <math.h>
#include <stdint.h>

// Dims
#define BN    256      // B*N
#define UVD   49       // U*V
#define STD_  64       // S*T
#define CHD   8
#define AD    98
#define MD    128
#define CD    16

#define ZSZ   (BN*AD*MD*CD)      // 51,380,224 elements
#define T2SZ  (BN*AD*STD_*CHD)   // 12,845,056
#define PVSZ  (AD*MD*CD)         // 200,704

typedef unsigned short u16;

// ---- bf16 helpers (internal storage bf16, compute fp32) ----
__device__ __forceinline__ float bflo(uint32_t u) {
    return __builtin_bit_cast(float, u << 16);
}
__device__ __forceinline__ float bfhi(uint32_t u) {
    return __builtin_bit_cast(float, u & 0xFFFF0000u);
}
__device__ __forceinline__ uint32_t packbf(float lo, float hi) {  // RNE pack 2 fp32 -> 2 bf16
    uint32_t a = __builtin_bit_cast(uint32_t, lo);
    uint32_t b = __builtin_bit_cast(uint32_t, hi);
    a = (a + 0x7FFFu + ((a >> 16) & 1u)) >> 16;
    b = (b + 0x7FFFu + ((b >> 16) & 1u)) >> 16;
    return a | (b << 16);
}

__device__ __forceinline__ void fma4(float4& a, const float4& v, float s) {
    a.x = fmaf(v.x, s, a.x); a.y = fmaf(v.y, s, a.y);
    a.z = fmaf(v.z, s, a.z); a.w = fmaf(v.w, s, a.w);
}

__device__ __forceinline__ uint32_t hsh(uint32_t x) {
    x ^= x >> 16; x *= 0x7feb352dU;
    x ^= x >> 15; x *= 0x846ca68bU;
    x ^= x >> 16; return x;
}

__device__ __forceinline__ float blockReduceSum256(float s) {
    __shared__ float sw[4];
    #pragma unroll
    for (int o = 32; o > 0; o >>= 1) s += __shfl_down(s, o, 64);
    int lane = threadIdx.x & 63, wi = threadIdx.x >> 6;
    if (lane == 0) sw[wi] = s;
    __syncthreads();
    return sw[0] + sw[1] + sw[2] + sw[3];
}

// ---------------- prep: dsT + three Gram matrices, one launch ----------------

__global__ __launch_bounds__(256) void k_prep(const float* __restrict__ da, const float* __restrict__ ds,
                                              const float* __restrict__ dc,
                                              float* __restrict__ dsT, float* __restrict__ Ga,
                                              float* __restrict__ Gs, float* __restrict__ Gc) {
    int i = blockIdx.x * 256 + threadIdx.x;
    if (i < 8192) {                       // dsT[st*128+m]
        int st = i >> 7, m = i & 127;
        dsT[i] = ds[m * 64 + st];
        return;
    }
    int j = i - 8192;
    if (j < 9604) {                       // Ga 98x98
        int a = j / 98, b = j % 98;
        float s = 0.f;
        for (int uv = 0; uv < 49; ++uv) s = fmaf(da[a * 49 + uv], da[b * 49 + uv], s);
        Ga[j] = s;
        return;
    }
    int k = j - 9604;
    if (k < 16384) {                      // Gs 128x128
        int m = k >> 7, n = k & 127;
        float s = 0.f;
        for (int st = 0; st < 64; ++st) s = fmaf(ds[m * 64 + st], ds[n * 64 + st], s);
        Gs[k] = s;
        return;
    }
    int l = k - 16384;
    if (l < 256) {                        // Gc 16x16
        int c = l >> 4, d = l & 15;
        float s = 0.f;
        for (int h = 0; h < 8; ++h) s = fmaf(dc[c * 8 + h], dc[d * 8 + h], s);
        Gc[l] = s;
    }
}

// ---------------- joint 10-iter power iteration (matches reference truncation) ----------------

__global__ __launch_bounds__(256) void k_v0(float* __restrict__ v) {
    int i = blockIdx.x * 256 + threadIdx.x;
    if (i >= PVSZ) return;
    uint32_t h1 = hsh((uint32_t)(i * 2 + 1));
    uint32_t h2 = hsh((uint32_t)(i * 2 + 2) ^ 0x9e3779b9U);
    float u1 = ((float)h1 + 1.0f) * (1.0f / 4294967808.0f);   // (0,1)
    float u2 = (float)h2 * (1.0f / 4294967296.0f);
    v[i] = sqrtf(-2.f * logf(u1)) * cosf(6.28318530718f * u2);
}

__global__ __launch_bounds__(256) void k_ata1(const float* __restrict__ v, const float* __restrict__ Gc,
                                              float* __restrict__ w1) {
    int p = blockIdx.x * 256 + threadIdx.x;   // a*128+m
    if (p >= AD * MD) return;
    float vv[16];
    const float4* vp = (const float4*)(v + p * 16);
    #pragma unroll
    for (int j = 0; j < 4; ++j) {
        float4 t = vp[j];
        vv[4*j] = t.x; vv[4*j+1] = t.y; vv[4*j+2] = t.z; vv[4*j+3] = t.w;
    }
    float4* op = (float4*)(w1 + p * 16);
    #pragma unroll
    for (int j = 0; j < 4; ++j) {
        float o[4];
        #pragma unroll
        for (int k = 0; k < 4; ++k) {
            int d = 4*j + k;
            float s = 0.f;
            #pragma unroll
            for (int c = 0; c < 16; ++c) s = fmaf(vv[c], Gc[c * 16 + d], s);
            o[k] = s;
        }
        op[j] = make_float4(o[0], o[1], o[2], o[3]);
    }
}

__global__ __launch_bounds__(256) void k_ata2(const float* __restrict__ w1, const float* __restrict__ Gs,
                                              float* __restrict__ w2) {
    __shared__ float w1a[MD * CD];
    int a = blockIdx.x, t = threadIdx.x;
    for (int e = t; e < MD * CD; e += 256) w1a[e] = w1[a * MD * CD + e];
    __syncthreads();
    for (int o = t; o < MD * CD; o += 256) {
        int n = o >> 4, d = o & 15;
        float s = 0.f;
        for (int m = 0; m < MD; ++m) s = fmaf(w1a[m * 16 + d], Gs[m * 128 + n], s);
        w2[a * 2048 + o] = s;
    }
}

__global__ __launch_bounds__(256) void k_ata3(const float* __restrict__ w2, const float* __restrict__ Ga,
                                              float* __restrict__ wv) {
    __shared__ float w2n[AD * CD];
    __shared__ float gal[AD * AD];
    int n = blockIdx.x, t = threadIdx.x;
    for (int e = t; e < AD * CD; e += 256) {
        int a = e >> 4, d = e & 15;
        w2n[e] = w2[a * 2048 + n * 16 + d];
    }
    for (int e = t; e < AD * AD; e += 256) gal[e] = Ga[e];
    __syncthreads();
    for (int o = t; o < AD * CD; o += 256) {
        int b = o >> 4, d = o & 15;
        float s = 0.f;
        for (int a = 0; a < AD; ++a) s = fmaf(w2n[a * 16 + d], gal[a * 98 + b], s);
        wv[b * 2048 + n * 16 + d] = s;
    }
}

__global__ __launch_bounds__(256) void k_red1(const float* __restrict__ wv, float* __restrict__ part) {
    int i = blockIdx.x * 256 + threadIdx.x;   // grid exactly 784*256 = PVSZ
    float x = wv[i];
    float tot = blockReduceSum256(x * x);
    if (threadIdx.x == 0) part[blockIdx.x] = tot;
}

__global__ __launch_bounds__(256) void k_norm(const float* __restrict__ wv, const float* __restrict__ part,
                                              float* __restrict__ v) {
    int t = threadIdx.x;
    float s = 0.f;
    for (int i = t; i < 784; i += 256) s += part[i];
    float tot = blockReduceSum256(s);
    float nrm = sqrtf(tot);
    float sc = 1.f / (nrm + 1e-12f);
    int i = blockIdx.x * 256 + t;
    v[i] = wv[i] * sc;
}

__global__ __launch_bounds__(256) void k_L(const float* __restrict__ part, float* __restrict__ scal) {
    int t = threadIdx.x;
    float s = 0.f;
    for (int i = t; i < 784; i += 256) s += part[i];
    float tot = blockReduceSum256(s);
    if (t == 0) {
        float L = fmaxf(sqrtf(tot), 1e-6f);
        scal[1] = 1.f / L;      // step
        scal[2] = 0.1f / L;     // thr = COUPLE/L
    }
}

// ---------------- FISTA fused kernels ----------------

// Fused recon_a + adj_a, st-chunked (8 st = 64 elems per chunk, 8 chunks), in-place on t2 (bf16).
template<int FIRSTX>
__global__ __launch_bounds__(256) void k_fusedA(const u16* t2g, const float* __restrict__ da,
                                                const float* __restrict__ xg, u16* t2o) {
    __shared__ float l_in[98 * 66];    // 25.3 KB
    __shared__ float l_r[49 * 68];     // 13.0 KB
    int ch = blockIdx.x, bn = blockIdx.y, t = threadIdx.x;
    int base = ch * 64;                // element offset within 512-row (8 st * 8 h)
    if (!FIRSTX) {
        for (int e8 = t; e8 < 784; e8 += 256) {           // 98 a * 8 uint4 (8 bf16 each)
            int a = e8 >> 3, r8 = e8 & 7;
            uint4 v = *(const uint4*)&t2g[(size_t)(bn * 98 + a) * 512 + base + r8 * 8];
            float* d = &l_in[a * 66 + r8 * 8];
            d[0] = bflo(v.x); d[1] = bfhi(v.x); d[2] = bflo(v.y); d[3] = bfhi(v.y);
            d[4] = bflo(v.z); d[5] = bfhi(v.z); d[6] = bflo(v.w); d[7] = bfhi(v.w);
        }
        __syncthreads();
        for (int e2 = t; e2 < 1568; e2 += 256) {          // 49 uv * 32 pairs
            int uv = e2 >> 5, i2 = (e2 & 31) * 2;
            float s0 = 0.f, s1 = 0.f;
            for (int a = 0; a < 98; ++a) {
                float w = da[a * 49 + uv];
                s0 = fmaf(l_in[a * 66 + i2], w, s0);
                s1 = fmaf(l_in[a * 66 + i2 + 1], w, s1);
            }
            float2 xv = *(const float2*)&xg[(size_t)bn * 25088 + uv * 512 + base + i2];
            l_r[uv * 68 + i2]     = s0 - xv.x;
            l_r[uv * 68 + i2 + 1] = s1 - xv.y;
        }
    } else {
        for (int e2 = t; e2 < 1568; e2 += 256) {
            int uv = e2 >> 5, i2 = (e2 & 31) * 2;
            float2 xv = *(const float2*)&xg[(size_t)bn * 25088 + uv * 512 + base + i2];
            l_r[uv * 68 + i2]     = -xv.x;
            l_r[uv * 68 + i2 + 1] = -xv.y;
        }
    }
    __syncthreads();
    for (int e2 = t; e2 < 3136; e2 += 256) {              // 98 a * 32 pairs
        int a = e2 >> 5, i2 = (e2 & 31) * 2;
        float s0 = 0.f, s1 = 0.f;
        for (int uv = 0; uv < 49; ++uv) {
            float w = da[a * 49 + uv];
            s0 = fmaf(l_r[uv * 68 + i2], w, s0);
            s1 = fmaf(l_r[uv * 68 + i2 + 1], w, s1);
        }
        *(uint32_t*)&t2o[(size_t)(bn * 98 + a) * 512 + base + i2] = packbf(s0, s1);
    }
}

// Fused adj_s + (x dc^T) + FISTA update + (x dc) + recon_s, per (bn,a) slice, in-place on t2.
// z ping-pong: zc = z_{j-1} (read), zp = z_{j-2} (read when betaPrev!=0, overwritten with z_j).
__global__ __launch_bounds__(256) void k_fused(const u16* t2g, u16* t2o,
                                               const float* __restrict__ dsT, const float* __restrict__ ds,
                                               const float* __restrict__ dc, const float* __restrict__ scal,
                                               const u16* __restrict__ zc, u16* zp,
                                               float betaPrev, float beta, int first, int last) {
    __shared__ float l_t2[512];        // 2 KB
    __shared__ float l_t1b[128 * 9];   // 4.6 KB
    __shared__ float l_po[128 * 10];   // 5.1 KB (stride 10 keeps b64 reads 8B-aligned)
    __shared__ float l_dc[128];
    int p = blockIdx.x, t = threadIdx.x;

    // stage 0: loads (dsT/ds stay in global: 8-lane-shared addresses dedupe in L1)
    if (t < 64) {
        uint4 v = *(const uint4*)&t2g[(size_t)p * 512 + t * 8];
        float* d = &l_t2[t * 8];
        d[0] = bflo(v.x); d[1] = bfhi(v.x); d[2] = bflo(v.y); d[3] = bfhi(v.y);
        d[4] = bflo(v.z); d[5] = bfhi(v.z); d[6] = bflo(v.w); d[7] = bfhi(v.w);
    }
    if (t >= 128) l_dc[t - 128] = dc[t - 128];
    __syncthreads();

    // stage A: t1b[m,h] = sum_st t2[st,h] * ds[m,st]   (dsT from global, L1-broadcast)
    {
        int h = t & 7, mg = t >> 3;    // mg 0..31 -> 4 m's
        float4 acc = make_float4(0.f, 0.f, 0.f, 0.f);
        const float* dp = dsT + mg * 4;
        #pragma unroll 4
        for (int st = 0; st < 64; ++st) {
            float v = l_t2[st * 8 + h];
            float4 d4 = *(const float4*)(dp + st * 128);
            fma4(acc, d4, v);
        }
        l_t1b[(mg * 4 + 0) * 9 + h] = acc.x;
        l_t1b[(mg * 4 + 1) * 9 + h] = acc.y;
        l_t1b[(mg * 4 + 2) * 9 + h] = acc.z;
        l_t1b[(mg * 4 + 3) * 9 + h] = acc.w;
    }
    __syncthreads();

    // stage B (threads 0..127, thread = m owning all 16 c):
    if (t < 128) {
        int m = t;
        float tb[8];
        #pragma unroll
        for (int h = 0; h < 8; ++h) tb[h] = l_t1b[m * 9 + h];
        float step = scal[1], thr = scal[2];
        size_t q = (size_t)p * 2048 + (size_t)m * 16;
        float o[8];
        #pragma unroll
        for (int h = 0; h < 8; ++h) o[h] = 0.f;
        #pragma unroll
        for (int half = 0; half < 2; ++half) {
            float g8[8];
            #pragma unroll
            for (int cc = 0; cc < 8; ++cc) {
                int c = half * 8 + cc;
                float s = 0.f;
                #pragma unroll
                for (int h = 0; h < 8; ++h) s = fmaf(tb[h], l_dc[c * 8 + h], s);
                g8[cc] = s;
            }
            float zcv[8], zpv[8];
            #pragma unroll
            for (int cc = 0; cc < 8; ++cc) { zcv[cc] = 0.f; zpv[cc] = 0.f; }
            if (!first) {
                uint4 a = *(const uint4*)&zc[q + half * 8];
                zcv[0] = bflo(a.x); zcv[1] = bfhi(a.x); zcv[2] = bflo(a.y); zcv[3] = bfhi(a.y);
                zcv[4] = bflo(a.z); zcv[5] = bfhi(a.z); zcv[6] = bflo(a.w); zcv[7] = bfhi(a.w);
                if (betaPrev != 0.0f) {
                    uint4 b = *(const uint4*)&zp[q + half * 8];
                    zpv[0] = bflo(b.x); zpv[1] = bfhi(b.x); zpv[2] = bflo(b.y); zpv[3] = bfhi(b.y);
                    zpv[4] = bflo(b.z); zpv[5] = bfhi(b.z); zpv[6] = bflo(b.w); zpv[7] = bfhi(b.w);
                }
            }
            float zn8[8], src8[8];
            #pragma unroll
            for (int cc = 0; cc < 8; ++cc) {
                float y  = fmaf(betaPrev, zcv[cc] - zpv[cc], zcv[cc]);  // y_{j-1}
                float pv = fmaf(-step, g8[cc], y);
                float av = fabsf(pv) - thr;
                float z1 = (av > 0.f) ? copysignf(av, pv) : 0.f;
                zn8[cc] = z1;
                src8[cc] = last ? z1 : fmaf(beta, z1 - zcv[cc], z1);    // y_j
            }
            if (!last) {
                uint4 ov;
                ov.x = packbf(zn8[0], zn8[1]); ov.y = packbf(zn8[2], zn8[3]);
                ov.z = packbf(zn8[4], zn8[5]); ov.w = packbf(zn8[6], zn8[7]);
                *(uint4*)&zp[q + half * 8] = ov;
            }
            #pragma unroll
            for (int cc = 0; cc < 8; ++cc) {
                #pragma unroll
                for (int h = 0; h < 8; ++h)
                    o[h] = fmaf(src8[cc], l_dc[(half * 8 + cc) * 8 + h], o[h]);
            }
        }
        #pragma unroll
        for (int h = 0; h < 8; ++h) l_po[m * 10 + h] = o[h];
    }
    __syncthreads();

    // stage C: t2o[st,h] = sum_m o[m,h] * ds[m,st]  (dsT float4 from global, po b64 broadcast)
    {
        int e0 = 2 * t, st = e0 >> 3, h0 = e0 & 7;   // h0 even
        float a0 = 0.f, a1 = 0.f;
        const float* dp = dsT + st * 128;
        #pragma unroll 4
        for (int mq = 0; mq < 32; ++mq) {
            float4 w4 = *(const float4*)(dp + mq * 4);
            float2 s0 = *(const float2*)&l_po[(mq * 4 + 0) * 10 + h0];
            float2 s1 = *(const float2*)&l_po[(mq * 4 + 1) * 10 + h0];
            float2 s2 = *(const float2*)&l_po[(mq * 4 + 2) * 10 + h0];
            float2 s3 = *(const float2*)&l_po[(mq * 4 + 3) * 10 + h0];
            a0 = fmaf(s0.x, w4.x, a0); a1 = fmaf(s0.y, w4.x, a1);
            a0 = fmaf(s1.x, w4.y, a0); a1 = fmaf(s1.y, w4.y, a1);
            a0 = fmaf(s2.x, w4.z, a0); a1 = fmaf(s2.y, w4.z, a1);
            a0 = fmaf(s3.x, w4.w, a0); a1 = fmaf(s3.y, w4.w, a1);
        }
        *(uint32_t*)&t2o[(size_t)p * 512 + e0] = packbf(a0, a1);
    }
}

// Final angular recon: out[bn,uv,st,h] = sum_a t2[bn,a,st,h]*da[a,uv]  (fp32 out)
__global__ __launch_bounds__(128) void k_recon_out(const u16* __restrict__ t2, const float* __restrict__ da,
                                                   float* __restrict__ out) {
    __shared__ float lt2[16 * 512];
    int uvg = blockIdx.x, bn = blockIdx.y, t = threadIdx.x;
    float4 acc[7];
    #pragma unroll
    for (int u = 0; u < 7; ++u) acc[u] = make_float4(0.f, 0.f, 0.f, 0.f);
    for (int c0 = 0; c0 < AD; c0 += 16) {
        int na = min(16, AD - c0);
        for (int e8 = t; e8 < na * 64; e8 += 128) {
            uint4 v = *(const uint4*)&t2[(size_t)(bn * AD + c0) * 512 + e8 * 8];
            float* d = &lt2[e8 * 8];
            d[0] = bflo(v.x); d[1] = bfhi(v.x); d[2] = bflo(v.y); d[3] = bfhi(v.y);
            d[4] = bflo(v.z); d[5] = bfhi(v.z); d[6] = bflo(v.w); d[7] = bfhi(v.w);
        }
        __syncthreads();
        for (int al = 0; al < na; ++al) {
            float4 rv = *(const float4*)&lt2[al * 512 + t * 4];
            int a = c0 + al;
            #pragma unroll
            for (int u = 0; u < 7; ++u)
                fma4(acc[u], rv, da[a * 49 + uvg * 7 + u]);
        }
        __syncthreads();
    }
    #pragma unroll
    for (int u = 0; u < 7; ++u) {
        size_t idx = (size_t)bn * 25088 + (uvg * 7 + u) * 512 + t * 4;
        *(float4*)&out[idx] = acc[u];
    }
}

// ---------------- launcher ----------------

extern "C" void kernel_launch(void* const* d_in, const int* in_sizes, int n_in,
                              void* d_out, int out_size, void* d_ws, size_t ws_size,
                              hipStream_t stream) {
    const float* x  = (const float*)d_in[0];
    const float* da = (const float*)d_in[1];
    const float* ds = (const float*)d_in[2];
    const float* dc = (const float*)d_in[3];
    float* out = (float*)d_out;

    char* base = (char*)d_ws;
    u16* Za = (u16*)base; base += (size_t)ZSZ * 2;    // 102.76 MB
    u16* Zb = (u16*)base; base += (size_t)ZSZ * 2;    // 102.76 MB
    u16* t2 = (u16*)base; base += (size_t)T2SZ * 2;   // 25.69 MB
    float* fb = (float*)base;
    size_t off = 0;
    float* dsT  = fb + off; off += 8192;
    float* Ga   = fb + off; off += 9604;
    float* Gs   = fb + off; off += 16384;
    float* Gc   = fb + off; off += 256;
    float* v    = fb + off; off += PVSZ;
    float* w1   = fb + off; off += PVSZ;
    float* w2   = fb + off; off += PVSZ;
    float* wv   = fb + off; off += PVSZ;
    float* part = fb + off; off += 784;
    float* scal = fb + off; off += 4;
    (void)ws_size; (void)in_sizes; (void)n_in; (void)out_size;

    // ---- prep + joint 10-iter power iteration for L (matches reference truncation) ----
    k_prep<<<135, 256, 0, stream>>>(da, ds, dc, dsT, Ga, Gs, Gc);
    k_v0<<<784, 256, 0, stream>>>(v);
    for (int it = 0; it < 10; ++it) {
        k_ata1<<<49, 256, 0, stream>>>(v, Gc, w1);
        k_ata2<<<98, 256, 0, stream>>>(w1, Gs, w2);
        k_ata3<<<128, 256, 0, stream>>>(w2, Ga, wv);
        k_red1<<<784, 256, 0, stream>>>(wv, part);
        k_norm<<<784, 256, 0, stream>>>(wv, part, v);
    }
    k_L<<<1, 256, 0, stream>>>(part, scal);

    // ---- beta schedule (host, matches reference t-recurrence) ----
    float betaArr[16];
    betaArr[0] = 0.f;
    double tprev = 1.0;
    for (int j = 1; j <= 15; ++j) {
        double tn = (1.0 + sqrt(1.0 + 4.0 * tprev * tprev)) * 0.5;
        betaArr[j] = (float)((tprev - 1.0) / tn);
        tprev = tn;
    }

    // ---- FISTA: 15 iterations ----
    u16* zbufs[2] = { Za, Zb };
    for (int j = 1; j <= 15; ++j) {
        if (j == 1) {
            k_fusedA<1><<<dim3(8, 256), 256, 0, stream>>>(t2, da, x, t2);
        } else {
            k_fusedA<0><<<dim3(8, 256), 256, 0, stream>>>(t2, da, x, t2);
        }
        const u16* zc = zbufs[1 - (j & 1)];   // z_{j-1}
        u16* zp = zbufs[j & 1];               // z_{j-2} -> becomes z_j
        k_fused<<<BN * AD, 256, 0, stream>>>(t2, t2, dsT, ds, dc, scal, zc, zp,
                                             (j >= 2) ? betaArr[j - 1] : 0.f, betaArr[j],
                                             (j == 1) ? 1 : 0, (j == 15) ? 1 : 0);
    }

    // ---- final recon(z15) -> out (t2 already = z15 x dc x ds) ----
    k_recon_out<<<dim3(7, 256), 128, 0, stream>>>(t2, da, out);
}

// Round 7
// 3687.851 us; speedup vs baseline: 2.0349x; 2.0349x over previous
//
#include <hip/hip_runtime.h>
#include <math.h>
#include <stdint.h>

// Dims
#define BN    256      // B*N
#define UVD   49       // U*V
#define STD_  64       // S*T
#define CHD   8
#define AD    98
#define MD    128
#define CD    16

#define ZSZ   (BN*AD*MD*CD)      // 51,380,224 elements
#define T2SZ  (BN*AD*STD_*CHD)   // 12,845,056
#define PVSZ  (AD*MD*CD)         // 200,704

typedef unsigned short u16;
typedef __attribute__((ext_vector_type(8))) short bf16x8;
typedef __attribute__((ext_vector_type(4))) float f32x4;

// ---- bf16 helpers (internal storage bf16, compute fp32) ----
__device__ __forceinline__ float bflo(uint32_t u) {
    return __builtin_bit_cast(float, u << 16);
}
__device__ __forceinline__ float bfhi(uint32_t u) {
    return __builtin_bit_cast(float, u & 0xFFFF0000u);
}
__device__ __forceinline__ uint32_t packbf(float lo, float hi) {  // RNE pack 2 fp32 -> 2 bf16
    uint32_t a = __builtin_bit_cast(uint32_t, lo);
    uint32_t b = __builtin_bit_cast(uint32_t, hi);
    a = (a + 0x7FFFu + ((a >> 16) & 1u)) >> 16;
    b = (b + 0x7FFFu + ((b >> 16) & 1u)) >> 16;
    return a | (b << 16);
}
__device__ __forceinline__ u16 bf1(float f) {   // RNE fp32 -> bf16
    uint32_t a = __builtin_bit_cast(uint32_t, f);
    a = (a + 0x7FFFu + ((a >> 16) & 1u)) >> 16;
    return (u16)a;
}

__device__ __forceinline__ void fma4(float4& a, const float4& v, float s) {
    a.x = fmaf(v.x, s, a.x); a.y = fmaf(v.y, s, a.y);
    a.z = fmaf(v.z, s, a.z); a.w = fmaf(v.w, s, a.w);
}

__device__ __forceinline__ uint32_t hsh(uint32_t x) {
    x ^= x >> 16; x *= 0x7feb352dU;
    x ^= x >> 15; x *= 0x846ca68bU;
    x ^= x >> 16; return x;
}

__device__ __forceinline__ float blockReduceSum256(float s) {
    __shared__ float sw[4];
    #pragma unroll
    for (int o = 32; o > 0; o >>= 1) s += __shfl_down(s, o, 64);
    int lane = threadIdx.x & 63, wi = threadIdx.x >> 6;
    if (lane == 0) sw[wi] = s;
    __syncthreads();
    return sw[0] + sw[1] + sw[2] + sw[3];
}

// ---------------- prep: fragment-ordered ds (bf16) + Gram matrices ----------------
// dsAg: stage-A A-frags: A[m][k=st]; frag f=(mt*2+kc): elem = ds[(mt*16+(L&15))*64 + kc*32+(L>>4)*8+j]
// dsCg: stage-C A-frags: A2[st][k=m]; frag f=(mt2*4+kc): elem = ds[(kc*32+(L>>4)*8+j)*64 + mt2*16+(L&15)]
__global__ __launch_bounds__(256) void k_prep(const float* __restrict__ da, const float* __restrict__ ds,
                                              const float* __restrict__ dc,
                                              u16* __restrict__ dsAg, u16* __restrict__ dsCg,
                                              float* __restrict__ Ga, float* __restrict__ Gs,
                                              float* __restrict__ Gc) {
    int i = blockIdx.x * 256 + threadIdx.x;
    if (i < 8192) {
        int f = i >> 9, r = i & 511, L = r >> 3, j = r & 7;
        int mt = f >> 1, kc = f & 1;
        int m = mt * 16 + (L & 15), st = kc * 32 + (L >> 4) * 8 + j;
        dsAg[i] = bf1(ds[m * 64 + st]);
        return;
    }
    int i2 = i - 8192;
    if (i2 < 8192) {
        int f = i2 >> 9, r = i2 & 511, L = r >> 3, j = r & 7;
        int mt2 = f >> 2, kc = f & 3;
        int st = mt2 * 16 + (L & 15), m = kc * 32 + (L >> 4) * 8 + j;
        dsCg[i2] = bf1(ds[m * 64 + st]);
        return;
    }
    int jg = i2 - 8192;
    if (jg < 9604) {                       // Ga 98x98
        int a = jg / 98, b = jg % 98;
        float s = 0.f;
        for (int uv = 0; uv < 49; ++uv) s = fmaf(da[a * 49 + uv], da[b * 49 + uv], s);
        Ga[jg] = s;
        return;
    }
    int k = jg - 9604;
    if (k < 16384) {                       // Gs 128x128
        int m = k >> 7, n = k & 127;
        float s = 0.f;
        for (int st = 0; st < 64; ++st) s = fmaf(ds[m * 64 + st], ds[n * 64 + st], s);
        Gs[k] = s;
        return;
    }
    int l = k - 16384;
    if (l < 256) {                         // Gc 16x16
        int c = l >> 4, d = l & 15;
        float s = 0.f;
        for (int h = 0; h < 8; ++h) s = fmaf(dc[c * 8 + h], dc[d * 8 + h], s);
        Gc[l] = s;
    }
}

// ---------------- joint 10-iter power iteration (matches reference truncation) ----------------

__global__ __launch_bounds__(256) void k_v0(float* __restrict__ v) {
    int i = blockIdx.x * 256 + threadIdx.x;
    if (i >= PVSZ) return;
    uint32_t h1 = hsh((uint32_t)(i * 2 + 1));
    uint32_t h2 = hsh((uint32_t)(i * 2 + 2) ^ 0x9e3779b9U);
    float u1 = ((float)h1 + 1.0f) * (1.0f / 4294967808.0f);
    float u2 = (float)h2 * (1.0f / 4294967296.0f);
    v[i] = sqrtf(-2.f * logf(u1)) * cosf(6.28318530718f * u2);
}

__global__ __launch_bounds__(256) void k_ata1(const float* __restrict__ v, const float* __restrict__ Gc,
                                              float* __restrict__ w1) {
    int p = blockIdx.x * 256 + threadIdx.x;
    if (p >= AD * MD) return;
    float vv[16];
    const float4* vp = (const float4*)(v + p * 16);
    #pragma unroll
    for (int j = 0; j < 4; ++j) {
        float4 t = vp[j];
        vv[4*j] = t.x; vv[4*j+1] = t.y; vv[4*j+2] = t.z; vv[4*j+3] = t.w;
    }
    float4* op = (float4*)(w1 + p * 16);
    #pragma unroll
    for (int j = 0; j < 4; ++j) {
        float o[4];
        #pragma unroll
        for (int k = 0; k < 4; ++k) {
            int d = 4*j + k;
            float s = 0.f;
            #pragma unroll
            for (int c = 0; c < 16; ++c) s = fmaf(vv[c], Gc[c * 16 + d], s);
            o[k] = s;
        }
        op[j] = make_float4(o[0], o[1], o[2], o[3]);
    }
}

__global__ __launch_bounds__(256) void k_ata2(const float* __restrict__ w1, const float* __restrict__ Gs,
                                              float* __restrict__ w2) {
    __shared__ float w1a[MD * CD];
    int a = blockIdx.x, t = threadIdx.x;
    for (int e = t; e < MD * CD; e += 256) w1a[e] = w1[a * MD * CD + e];
    __syncthreads();
    for (int o = t; o < MD * CD; o += 256) {
        int n = o >> 4, d = o & 15;
        float s = 0.f;
        for (int m = 0; m < MD; ++m) s = fmaf(w1a[m * 16 + d], Gs[m * 128 + n], s);
        w2[a * 2048 + o] = s;
    }
}

__global__ __launch_bounds__(256) void k_ata3(const float* __restrict__ w2, const float* __restrict__ Ga,
                                              float* __restrict__ wv) {
    __shared__ float w2n[AD * CD];
    __shared__ float gal[AD * AD];
    int n = blockIdx.x, t = threadIdx.x;
    for (int e = t; e < AD * CD; e += 256) {
        int a = e >> 4, d = e & 15;
        w2n[e] = w2[a * 2048 + n * 16 + d];
    }
    for (int e = t; e < AD * AD; e += 256) gal[e] = Ga[e];
    __syncthreads();
    for (int o = t; o < AD * CD; o += 256) {
        int b = o >> 4, d = o & 15;
        float s = 0.f;
        for (int a = 0; a < AD; ++a) s = fmaf(w2n[a * 16 + d], gal[a * 98 + b], s);
        wv[b * 2048 + n * 16 + d] = s;
    }
}

__global__ __launch_bounds__(256) void k_red1(const float* __restrict__ wv, float* __restrict__ part) {
    int i = blockIdx.x * 256 + threadIdx.x;
    float x = wv[i];
    float tot = blockReduceSum256(x * x);
    if (threadIdx.x == 0) part[blockIdx.x] = tot;
}

__global__ __launch_bounds__(256) void k_norm(const float* __restrict__ wv, const float* __restrict__ part,
                                              float* __restrict__ v) {
    int t = threadIdx.x;
    float s = 0.f;
    for (int i = t; i < 784; i += 256) s += part[i];
    float tot = blockReduceSum256(s);
    float nrm = sqrtf(tot);
    float sc = 1.f / (nrm + 1e-12f);
    int i = blockIdx.x * 256 + t;
    v[i] = wv[i] * sc;
}

__global__ __launch_bounds__(256) void k_L(const float* __restrict__ part, float* __restrict__ scal) {
    int t = threadIdx.x;
    float s = 0.f;
    for (int i = t; i < 784; i += 256) s += part[i];
    float tot = blockReduceSum256(s);
    if (t == 0) {
        float L = fmaxf(sqrtf(tot), 1e-6f);
        scal[1] = 1.f / L;      // step
        scal[2] = 0.1f / L;     // thr = COUPLE/L
    }
}

// ---------------- FISTA fused kernels ----------------
// t2 layout is h-major: t2[p][h*64 + st], bf16.

// Fused recon_a + adj_a per (h-chunk, bn), in-place on t2.
template<int FIRSTX>
__global__ __launch_bounds__(256) void k_fusedA(u16* t2g, const float* __restrict__ da,
                                                const float* __restrict__ xg, u16* t2o) {
    __shared__ float l_in[98 * 66];    // 25.3 KB
    __shared__ float l_r[49 * 68];     // 13.0 KB
    int ch = blockIdx.x, bn = blockIdx.y, t = threadIdx.x;   // ch = h (0..7)
    int base = ch * 64;                // element offset within h-major 512-row
    size_t xbase = (size_t)bn * 25088;
    if (!FIRSTX) {
        for (int e8 = t; e8 < 784; e8 += 256) {           // 98 a * 8 uint4 (8 bf16 each)
            int a = e8 >> 3, r8 = e8 & 7;
            uint4 v = *(const uint4*)&t2g[(size_t)(bn * 98 + a) * 512 + base + r8 * 8];
            float* d = &l_in[a * 66 + r8 * 8];
            d[0] = bflo(v.x); d[1] = bfhi(v.x); d[2] = bflo(v.y); d[3] = bfhi(v.y);
            d[4] = bflo(v.z); d[5] = bfhi(v.z); d[6] = bflo(v.w); d[7] = bfhi(v.w);
        }
        __syncthreads();
        for (int e2 = t; e2 < 1568; e2 += 256) {          // 49 uv * 32 st-pairs
            int uv = e2 >> 5, i2 = (e2 & 31) * 2;         // i2 = st
            float s0 = 0.f, s1 = 0.f;
            for (int a = 0; a < 98; ++a) {
                float w = da[a * 49 + uv];
                s0 = fmaf(l_in[a * 66 + i2], w, s0);
                s1 = fmaf(l_in[a * 66 + i2 + 1], w, s1);
            }
            float x0 = xg[xbase + uv * 512 + i2 * 8 + ch];
            float x1 = xg[xbase + uv * 512 + (i2 + 1) * 8 + ch];
            l_r[uv * 68 + i2]     = s0 - x0;
            l_r[uv * 68 + i2 + 1] = s1 - x1;
        }
    } else {
        for (int e2 = t; e2 < 1568; e2 += 256) {
            int uv = e2 >> 5, i2 = (e2 & 31) * 2;
            float x0 = xg[xbase + uv * 512 + i2 * 8 + ch];
            float x1 = xg[xbase + uv * 512 + (i2 + 1) * 8 + ch];
            l_r[uv * 68 + i2]     = -x0;
            l_r[uv * 68 + i2 + 1] = -x1;
        }
    }
    __syncthreads();
    for (int e2 = t; e2 < 3136; e2 += 256) {              // 98 a * 32 st-pairs
        int a = e2 >> 5, i2 = (e2 & 31) * 2;
        float s0 = 0.f, s1 = 0.f;
        for (int uv = 0; uv < 49; ++uv) {
            float w = da[a * 49 + uv];
            s0 = fmaf(l_r[uv * 68 + i2], w, s0);
            s1 = fmaf(l_r[uv * 68 + i2 + 1], w, s1);
        }
        *(uint32_t*)&t2o[(size_t)(bn * 98 + a) * 512 + base + i2] = packbf(s0, s1);
    }
}

// MFMA-fused adj_s + dc^T + FISTA + dc + recon_s. Block = 4 waves x 2 slices = 8 slices.
// Stage A: t1b[m,(s,h)] = sum_st ds[m,st] * t2[(s,h),st]         (MFMA, K=64)
// Stage B: pointwise FISTA in (m,c), thread = m                   (VALU)
// Stage C: t2o[st,(s,h)] = sum_m ds[m,st] * o[(s,h),m]            (MFMA, K=128)
__global__ __launch_bounds__(256) void k_fused(u16* t2g,
                                               const u16* __restrict__ dsAg, const u16* __restrict__ dsCg,
                                               const float* __restrict__ dcg, const float* __restrict__ scal,
                                               const u16* __restrict__ zc, u16* __restrict__ zp,
                                               float betaPrev, float beta, int first, int last) {
    __shared__ short l_dsF[8192];      // 16 KB frag buffer (dsA then dsC)
    __shared__ float l_t1b[8448];      // [slice(8)][h(8)] rows stride 132 fp32, 33 KB
    __shared__ short l_o[8704];        // [slice(8)][h(8)] rows stride 136 bf16, 17 KB
    int t = threadIdx.x, w = t >> 6, L = t & 63;
    int quad = L >> 4, n = L & 15, s_n = n >> 3, h_n = n & 7;
    int P0 = blockIdx.x * 8 + w * 2;   // wave's first global slice

    // ---- pre-issue global loads: B-frags (stage A) + z streams ----
    bf16x8 Bf[2];
    #pragma unroll
    for (int kc = 0; kc < 2; ++kc)
        Bf[kc] = *(const bf16x8*)&t2g[(size_t)(P0 + s_n) * 512 + h_n * 64 + kc * 32 + quad * 8];
    uint4 zcr[8], zpr[8];
    bool haveZp = (!first) && (betaPrev != 0.0f);
    if (!first) {
        #pragma unroll
        for (int sl = 0; sl < 2; ++sl)
            #pragma unroll
            for (int mh = 0; mh < 2; ++mh) {
                size_t q = (size_t)(P0 + sl) * 2048 + (size_t)(mh * 64 + L) * 16;
                zcr[(sl * 2 + mh) * 2]     = *(const uint4*)&zc[q];
                zcr[(sl * 2 + mh) * 2 + 1] = *(const uint4*)&zc[q + 8];
            }
    }
    if (haveZp) {
        #pragma unroll
        for (int sl = 0; sl < 2; ++sl)
            #pragma unroll
            for (int mh = 0; mh < 2; ++mh) {
                size_t q = (size_t)(P0 + sl) * 2048 + (size_t)(mh * 64 + L) * 16;
                zpr[(sl * 2 + mh) * 2]     = *(const uint4*)&zp[q];
                zpr[(sl * 2 + mh) * 2 + 1] = *(const uint4*)&zp[q + 8];
            }
    }

    // stage dsA frags
    for (int i = t; i < 1024; i += 256) ((uint4*)l_dsF)[i] = ((const uint4*)dsAg)[i];
    __syncthreads();

    // ---- stage A (MFMA) ----
    f32x4 accA[8];
    #pragma unroll
    for (int mt = 0; mt < 8; ++mt) accA[mt] = (f32x4){0.f, 0.f, 0.f, 0.f};
    #pragma unroll
    for (int kc = 0; kc < 2; ++kc) {
        #pragma unroll
        for (int mt = 0; mt < 8; ++mt) {
            bf16x8 A = *(const bf16x8*)&l_dsF[(mt * 2 + kc) * 512 + L * 8];
            accA[mt] = __builtin_amdgcn_mfma_f32_16x16x32_bf16(A, Bf[kc], accA[mt], 0, 0, 0);
        }
    }
    {
        int col = ((w * 2 + s_n) * 8 + h_n) * 132;
        #pragma unroll
        for (int mt = 0; mt < 8; ++mt)
            *(f32x4*)&l_t1b[col + mt * 16 + quad * 4] = accA[mt];
    }
    __syncthreads();

    // restage frag buffer with dsC (used after next barrier)
    for (int i = t; i < 1024; i += 256) ((uint4*)l_dsF)[i] = ((const uint4*)dsCg)[i];

    // ---- stage B (VALU pointwise FISTA), thread = m, 4 (slice,m-half) regions ----
    float step = scal[1], thr = scal[2];
    #pragma unroll
    for (int sl = 0; sl < 2; ++sl) {
        int slK = w * 2 + sl;
        #pragma unroll
        for (int mh = 0; mh < 2; ++mh) {
            int m = mh * 64 + L, ri = sl * 2 + mh;
            float tb[8];
            #pragma unroll
            for (int h = 0; h < 8; ++h) tb[h] = l_t1b[(slK * 8 + h) * 132 + m];
            float g[16];
            #pragma unroll
            for (int c = 0; c < 16; ++c) {
                float s = 0.f;
                #pragma unroll
                for (int h = 0; h < 8; ++h) s = fmaf(tb[h], dcg[c * 8 + h], s);
                g[c] = s;
            }
            float zcv[16], zpv[16];
            #pragma unroll
            for (int c = 0; c < 16; ++c) { zcv[c] = 0.f; zpv[c] = 0.f; }
            if (!first) {
                uint4 a0 = zcr[ri * 2], a1 = zcr[ri * 2 + 1];
                zcv[0] = bflo(a0.x); zcv[1] = bfhi(a0.x); zcv[2] = bflo(a0.y); zcv[3] = bfhi(a0.y);
                zcv[4] = bflo(a0.z); zcv[5] = bfhi(a0.z); zcv[6] = bflo(a0.w); zcv[7] = bfhi(a0.w);
                zcv[8] = bflo(a1.x); zcv[9] = bfhi(a1.x); zcv[10] = bflo(a1.y); zcv[11] = bfhi(a1.y);
                zcv[12] = bflo(a1.z); zcv[13] = bfhi(a1.z); zcv[14] = bflo(a1.w); zcv[15] = bfhi(a1.w);
            }
            if (haveZp) {
                uint4 b0 = zpr[ri * 2], b1 = zpr[ri * 2 + 1];
                zpv[0] = bflo(b0.x); zpv[1] = bfhi(b0.x); zpv[2] = bflo(b0.y); zpv[3] = bfhi(b0.y);
                zpv[4] = bflo(b0.z); zpv[5] = bfhi(b0.z); zpv[6] = bflo(b0.w); zpv[7] = bfhi(b0.w);
                zpv[8] = bflo(b1.x); zpv[9] = bfhi(b1.x); zpv[10] = bflo(b1.y); zpv[11] = bfhi(b1.y);
                zpv[12] = bflo(b1.z); zpv[13] = bfhi(b1.z); zpv[14] = bflo(b1.w); zpv[15] = bfhi(b1.w);
            }
            float zn[16], src[16];
            #pragma unroll
            for (int c = 0; c < 16; ++c) {
                float y  = fmaf(betaPrev, zcv[c] - zpv[c], zcv[c]);  // y_{j-1}
                float pv = fmaf(-step, g[c], y);
                float av = fabsf(pv) - thr;
                float z1 = (av > 0.f) ? copysignf(av, pv) : 0.f;
                zn[c] = z1;
                src[c] = last ? z1 : fmaf(beta, z1 - zcv[c], z1);     // y_j
            }
            if (!last) {
                size_t q = (size_t)(P0 + sl) * 2048 + (size_t)m * 16;
                uint4 o0, o1;
                o0.x = packbf(zn[0], zn[1]);  o0.y = packbf(zn[2], zn[3]);
                o0.z = packbf(zn[4], zn[5]);  o0.w = packbf(zn[6], zn[7]);
                o1.x = packbf(zn[8], zn[9]);  o1.y = packbf(zn[10], zn[11]);
                o1.z = packbf(zn[12], zn[13]); o1.w = packbf(zn[14], zn[15]);
                *(uint4*)&zp[q] = o0;
                *(uint4*)&zp[q + 8] = o1;
            }
            #pragma unroll
            for (int h = 0; h < 8; ++h) {
                float s = 0.f;
                #pragma unroll
                for (int c = 0; c < 16; ++c) s = fmaf(src[c], dcg[c * 8 + h], s);
                l_o[(slK * 8 + h) * 136 + m] = (short)bf1(s);
            }
        }
    }
    __syncthreads();

    // ---- stage C (MFMA) ----
    f32x4 accC[4];
    #pragma unroll
    for (int mt2 = 0; mt2 < 4; ++mt2) accC[mt2] = (f32x4){0.f, 0.f, 0.f, 0.f};
    #pragma unroll
    for (int kc = 0; kc < 4; ++kc) {
        bf16x8 B2 = *(const bf16x8*)&l_o[((w * 2 + s_n) * 8 + h_n) * 136 + kc * 32 + quad * 8];
        #pragma unroll
        for (int mt2 = 0; mt2 < 4; ++mt2) {
            bf16x8 A2 = *(const bf16x8*)&l_dsF[(mt2 * 4 + kc) * 512 + L * 8];
            accC[mt2] = __builtin_amdgcn_mfma_f32_16x16x32_bf16(A2, B2, accC[mt2], 0, 0, 0);
        }
    }
    #pragma unroll
    for (int mt2 = 0; mt2 < 4; ++mt2) {
        uint2 ov = make_uint2(packbf(accC[mt2][0], accC[mt2][1]),
                              packbf(accC[mt2][2], accC[mt2][3]));
        *(uint2*)&t2g[(size_t)(P0 + s_n) * 512 + h_n * 64 + mt2 * 16 + quad * 4] = ov;
    }
}

// Final angular recon from h-major t2 -> st-major fp32 out (LDS transpose for coalesced writes)
__global__ __launch_bounds__(128) void k_recon_out(const u16* __restrict__ t2, const float* __restrict__ da,
                                                   float* __restrict__ out) {
    __shared__ float lt2[16 * 512];    // 32 KB
    __shared__ float l_t[7 * 520];     // 14.6 KB
    int uvg = blockIdx.x, bn = blockIdx.y, t = threadIdx.x;
    float4 acc[7];
    #pragma unroll
    for (int u = 0; u < 7; ++u) acc[u] = make_float4(0.f, 0.f, 0.f, 0.f);
    for (int c0 = 0; c0 < AD; c0 += 16) {
        int na = min(16, AD - c0);
        for (int e8 = t; e8 < na * 64; e8 += 128) {
            uint4 v = *(const uint4*)&t2[(size_t)(bn * AD + c0) * 512 + e8 * 8];
            float* d = &lt2[e8 * 8];
            d[0] = bflo(v.x); d[1] = bfhi(v.x); d[2] = bflo(v.y); d[3] = bfhi(v.y);
            d[4] = bflo(v.z); d[5] = bfhi(v.z); d[6] = bflo(v.w); d[7] = bfhi(v.w);
        }
        __syncthreads();
        for (int al = 0; al < na; ++al) {
            float4 rv = *(const float4*)&lt2[al * 512 + t * 4];
            int a = c0 + al;
            #pragma unroll
            for (int u = 0; u < 7; ++u)
                fma4(acc[u], rv, da[a * 49 + uvg * 7 + u]);
        }
        __syncthreads();
    }
    // transpose h-major -> st-major via LDS, then coalesced fp32 writes
    #pragma unroll
    for (int u = 0; u < 7; ++u)
        *(float4*)&l_t[u * 520 + t * 4] = acc[u];
    __syncthreads();
    for (int f = t; f < 896; f += 128) {
        int u = f >> 7, e4 = (f & 127) * 4;
        int st = e4 >> 3, h0 = e4 & 7;
        float4 o;
        o.x = l_t[u * 520 + (h0 + 0) * 64 + st];
        o.y = l_t[u * 520 + (h0 + 1) * 64 + st];
        o.z = l_t[u * 520 + (h0 + 2) * 64 + st];
        o.w = l_t[u * 520 + (h0 + 3) * 64 + st];
        *(float4*)&out[(size_t)bn * 25088 + (size_t)(uvg * 7 + u) * 512 + e4] = o;
    }
}

// ---------------- launcher ----------------

extern "C" void kernel_launch(void* const* d_in, const int* in_sizes, int n_in,
                              void* d_out, int out_size, void* d_ws, size_t ws_size,
                              hipStream_t stream) {
    const float* x  = (const float*)d_in[0];
    const float* da = (const float*)d_in[1];
    const float* ds = (const float*)d_in[2];
    const float* dc = (const float*)d_in[3];
    float* out = (float*)d_out;

    char* base = (char*)d_ws;
    u16* Za   = (u16*)base; base += (size_t)ZSZ * 2;    // 102.76 MB
    u16* Zb   = (u16*)base; base += (size_t)ZSZ * 2;    // 102.76 MB
    u16* t2   = (u16*)base; base += (size_t)T2SZ * 2;   // 25.69 MB
    u16* dsAg = (u16*)base; base += 8192 * 2;
    u16* dsCg = (u16*)base; base += 8192 * 2;
    float* fb = (float*)base;
    size_t off = 0;
    float* Ga   = fb + off; off += 9604;
    float* Gs   = fb + off; off += 16384;
    float* Gc   = fb + off; off += 256;
    float* v    = fb + off; off += PVSZ;
    float* w1   = fb + off; off += PVSZ;
    float* w2   = fb + off; off += PVSZ;
    float* wv   = fb + off; off += PVSZ;
    float* part = fb + off; off += 784;
    float* scal = fb + off; off += 4;
    (void)ws_size; (void)in_sizes; (void)n_in; (void)out_size;

    // ---- prep + joint 10-iter power iteration for L (matches reference truncation) ----
    k_prep<<<167, 256, 0, stream>>>(da, ds, dc, dsAg, dsCg, Ga, Gs, Gc);
    k_v0<<<784, 256, 0, stream>>>(v);
    for (int it = 0; it < 10; ++it) {
        k_ata1<<<49, 256, 0, stream>>>(v, Gc, w1);
        k_ata2<<<98, 256, 0, stream>>>(w1, Gs, w2);
        k_ata3<<<128, 256, 0, stream>>>(w2, Ga, wv);
        k_red1<<<784, 256, 0, stream>>>(wv, part);
        k_norm<<<784, 256, 0, stream>>>(wv, part, v);
    }
    k_L<<<1, 256, 0, stream>>>(part, scal);

    // ---- beta schedule (host, matches reference t-recurrence) ----
    float betaArr[16];
    betaArr[0] = 0.f;
    double tprev = 1.0;
    for (int j = 1; j <= 15; ++j) {
        double tn = (1.0 + sqrt(1.0 + 4.0 * tprev * tprev)) * 0.5;
        betaArr[j] = (float)((tprev - 1.0) / tn);
        tprev = tn;
    }

    // ---- FISTA: 15 iterations ----
    u16* zbufs[2] = { Za, Zb };
    for (int j = 1; j <= 15; ++j) {
        if (j == 1) {
            k_fusedA<1><<<dim3(8, 256), 256, 0, stream>>>(t2, da, x, t2);
        } else {
            k_fusedA<0><<<dim3(8, 256), 256, 0, stream>>>(t2, da, x, t2);
        }
        const u16* zc = zbufs[1 - (j & 1)];   // z_{j-1}
        u16* zp = zbufs[j & 1];               // z_{j-2} -> becomes z_j
        k_fused<<<3136, 256, 0, stream>>>(t2, dsAg, dsCg, dc, scal, zc, zp,
                                          (j >= 2) ? betaArr[j - 1] : 0.f, betaArr[j],
                                          (j == 1) ? 1 : 0, (j == 15) ? 1 : 0);
    }

    // ---- final recon(z15) -> out ----
    k_recon_out<<<dim3(7, 256), 128, 0, stream>>>(t2, da, out);
}